// Round 1
// baseline (1684.550 us; speedup 1.0000x reference)
//
#include <hip/hip_runtime.h>

// HarmonicFullyConnectedTensorProduct, lmax=2, MUL=64, B=1024, 11 paths.
//
// out[z,w,k] += sum_{u,v,m,n} x1[z,u,m] x2[z,v,n] W[p,w,u,v] C_p[m,n,k]
//
// Per u-step factorization:
//   c1[z,k,n] = sum_m x1[z,u,m] C[m,n,k]          (tiny)
//   T [z,v,k] = sum_n x2[z,v,n] c1[z,k,n]         (ZT*64*K1)
//   acc[z,w,k] += sum_v W[p,w,u,v] * T[z,v,k]     (the 18.8 GFLOP core)
//
// Input dict order (setup_inputs): x1_l0, x2_l0, x1_l1, x2_l1, x1_l2, x2_l2,
// W[11][64][64][64], C_0..C_10. Output: [1024][64][9] (l3 offsets 0,1,4).

#define NPATHS   11
#define ZT       16
#define NTHREADS 256

struct KArgs {
    const float* x1[3];
    const float* x2[3];
    const float* W;
    const float* C[NPATHS];
    float*       out;
};

template <int M1, int N1, int K1, int KOFF>
__device__ __forceinline__ void run_path(const float* __restrict__ x1g,
                                         const float* __restrict__ x2g,
                                         const float* __restrict__ Wg,   // = W + p*64*64*64
                                         const float* __restrict__ Cg,
                                         float* __restrict__ outg,
                                         int z0,
                                         float* __restrict__ sW,   // [64*65] (v-major, +1 pad)
                                         float* __restrict__ sT,   // [ZT*64*K1]
                                         float* __restrict__ sc1,  // [ZT*K1*N1]
                                         float* __restrict__ sC)   // [M1*N1*K1]
{
    const int t = threadIdx.x;

    // load C_p (<=125 floats)
    for (int i = t; i < M1 * N1 * K1; i += NTHREADS) sC[i] = Cg[i];
    __syncthreads();

    const int w  = t & 63;   // lane-consecutive w -> coalesced/conflict-free
    const int zq = t >> 6;   // wave id 0..3 -> z group (wave-uniform)

    float acc[4][K1];
#pragma unroll
    for (int zz = 0; zz < 4; ++zz)
#pragma unroll
        for (int k = 0; k < K1; ++k) acc[zz][k] = 0.f;

    for (int u = 0; u < 64; ++u) {
        // ---- stage W[p][w][u][v] -> sW[v*65 + w]  (global side coalesced in v)
        const float* wb = Wg + u * 64;
        for (int i = t; i < 4096; i += NTHREADS) {
            int ww = i >> 6, vv = i & 63;
            sW[vv * 65 + ww] = wb[ww * 4096 + vv];
        }
        // ---- B1: c1[z][k][n] = sum_m x1[z0+z][u][m] * C[m][n][k]
        for (int i = t; i < ZT * K1 * N1; i += NTHREADS) {
            int z = i / (K1 * N1);
            int r = i - z * (K1 * N1);
            int k = r / N1;
            int n = r - k * N1;
            float s = 0.f;
#pragma unroll
            for (int m = 0; m < M1; ++m)
                s += x1g[((z0 + z) * 64 + u) * M1 + m] * sC[(m * N1 + n) * K1 + k];
            sc1[(z * K1 + k) * N1 + n] = s;
        }
        __syncthreads();
        // ---- B2: sT[(z*64+v)*K1 + k] = sum_n x2[z0+z][v][n] * c1[z][k][n]
#pragma unroll
        for (int i2 = 0; i2 < (ZT * 64) / NTHREADS; ++i2) {
            int id = i2 * NTHREADS + t;
            int z = id >> 6, v = id & 63;
            float xv[N1];
#pragma unroll
            for (int n = 0; n < N1; ++n) xv[n] = x2g[((z0 + z) * 64 + v) * N1 + n];
#pragma unroll
            for (int k = 0; k < K1; ++k) {
                float s = 0.f;
#pragma unroll
                for (int n = 0; n < N1; ++n) s += xv[n] * sc1[(z * K1 + k) * N1 + n];
                sT[(z * 64 + v) * K1 + k] = s;
            }
        }
        __syncthreads();
        // ---- C: acc[zz][k] += W * T   (sW read conflict-free; sT wave-uniform broadcast)
#pragma unroll 4
        for (int v = 0; v < 64; ++v) {
            float wv = sW[v * 65 + w];
#pragma unroll
            for (int zz = 0; zz < 4; ++zz) {
                int z = zq * 4 + zz;
#pragma unroll
                for (int k = 0; k < K1; ++k)
                    acc[zz][k] += wv * sT[(z * 64 + v) * K1 + k];
            }
        }
        __syncthreads();
    }

    // ---- epilogue: out[z][w][KOFF+k] += acc  (<=4 paths collide per element)
#pragma unroll
    for (int zz = 0; zz < 4; ++zz) {
        int z = z0 + zq * 4 + zz;
#pragma unroll
        for (int k = 0; k < K1; ++k)
            atomicAdd(&outg[(size_t)z * 576 + w * 9 + KOFF + k], acc[zz][k]);
    }
}

__global__ __launch_bounds__(NTHREADS) void tp_kernel(KArgs a)
{
    __shared__ float sW[64 * 65];       // 16.6 KB
    __shared__ float sT[ZT * 64 * 5];   // 20 KB
    __shared__ float sc1[ZT * 5 * 5];   // 1.6 KB
    __shared__ float sC[125];

    const int z0 = blockIdx.x * ZT;
    const int p  = blockIdx.y;
    const float* Wg = a.W + (size_t)p * 64 * 64 * 64;

    switch (p) {
        case 0:  run_path<1,1,1,0>(a.x1[0], a.x2[0], Wg, a.C[0],  a.out, z0, sW, sT, sc1, sC); break;
        case 1:  run_path<1,3,3,1>(a.x1[0], a.x2[1], Wg, a.C[1],  a.out, z0, sW, sT, sc1, sC); break;
        case 2:  run_path<1,5,5,4>(a.x1[0], a.x2[2], Wg, a.C[2],  a.out, z0, sW, sT, sc1, sC); break;
        case 3:  run_path<3,1,3,1>(a.x1[1], a.x2[0], Wg, a.C[3],  a.out, z0, sW, sT, sc1, sC); break;
        case 4:  run_path<3,3,1,0>(a.x1[1], a.x2[1], Wg, a.C[4],  a.out, z0, sW, sT, sc1, sC); break;
        case 5:  run_path<3,3,5,4>(a.x1[1], a.x2[1], Wg, a.C[5],  a.out, z0, sW, sT, sc1, sC); break;
        case 6:  run_path<3,5,3,1>(a.x1[1], a.x2[2], Wg, a.C[6],  a.out, z0, sW, sT, sc1, sC); break;
        case 7:  run_path<5,1,5,4>(a.x1[2], a.x2[0], Wg, a.C[7],  a.out, z0, sW, sT, sc1, sC); break;
        case 8:  run_path<5,3,3,1>(a.x1[2], a.x2[1], Wg, a.C[8],  a.out, z0, sW, sT, sc1, sC); break;
        case 9:  run_path<5,5,1,0>(a.x1[2], a.x2[2], Wg, a.C[9],  a.out, z0, sW, sT, sc1, sC); break;
        case 10: run_path<5,5,5,4>(a.x1[2], a.x2[2], Wg, a.C[10], a.out, z0, sW, sT, sc1, sC); break;
        default: break;
    }
}

extern "C" void kernel_launch(void* const* d_in, const int* in_sizes, int n_in,
                              void* d_out, int out_size, void* d_ws, size_t ws_size,
                              hipStream_t stream)
{
    KArgs a;
    // setup_inputs() dict order: x1_l0, x2_l0, x1_l1, x2_l1, x1_l2, x2_l2, W, C_0..C_10
    a.x1[0] = (const float*)d_in[0];
    a.x2[0] = (const float*)d_in[1];
    a.x1[1] = (const float*)d_in[2];
    a.x2[1] = (const float*)d_in[3];
    a.x1[2] = (const float*)d_in[4];
    a.x2[2] = (const float*)d_in[5];
    a.W     = (const float*)d_in[6];
    for (int p = 0; p < NPATHS; ++p) a.C[p] = (const float*)d_in[7 + p];
    a.out   = (float*)d_out;

    // out is accumulated via atomics from 11 path-blocks -> must start at zero
    hipMemsetAsync(d_out, 0, (size_t)out_size * sizeof(float), stream);

    dim3 grid(1024 / ZT, NPATHS);
    tp_kernel<<<grid, NTHREADS, 0, stream>>>(a);
}

// Round 2
// 347.616 us; speedup vs baseline: 4.8460x; 4.8460x over previous
//
#include <hip/hip_runtime.h>

// HarmonicFullyConnectedTensorProduct, lmax=2, MUL=64, B=1024, 11 paths.
// out[z,w,k] += sum_{u,v,m,n} x1[z,u,m] x2[z,v,n] W[p,w,u,v] C_p[m,n,k]
//
// Per path: GEMM  D[w, z*K1+k] = sum_{u,v} W[w,u,v] * T[(u,v), z*K1+k]
//   T[(u,v),(z,k)] = sum_n x2[z,v,n] * c1[z,u,k,n];  c1 = sum_m x1[z,u,m] C[m,n,k]
// MFMA: mfma_f32_16x16x32_bf16. A = W slab (64w x 64v per u), B = T slab.
// Block = (path, z-tile of 64, u-chunk). u-split 1/2/4 for K1=1/3/5 -> 432 blocks.

#define NTHREADS 256

typedef __attribute__((ext_vector_type(4))) float f32x4;
typedef __attribute__((ext_vector_type(8))) short s16x8;

struct KArgs {
    const float* x1[3];
    const float* x2[3];
    const float* W;
    const float* C[11];
    float*       out;
};

__device__ __forceinline__ unsigned short f2bf(float x) {
    union { float f; unsigned u; } v; v.f = x;
    unsigned r = v.u + 0x7fffu + ((v.u >> 16) & 1u);   // round-to-nearest-even
    return (unsigned short)(r >> 16);
}

// LDS strides: 72 bf16 per row (144 B = 16B-multiple, 36 dwords -> uniform 8/bank on b128)
template <int M1, int N1, int K1, int KOFF, int USPLIT>
__device__ __forceinline__ void run_path(
    const float* __restrict__ x1g, const float* __restrict__ x2g,
    const float* __restrict__ Wg, const float* __restrict__ Cg,
    float* __restrict__ outg, int local,
    unsigned short* __restrict__ sW,   // [64][72] bf16
    unsigned short* __restrict__ sT,   // [64*K1][72] bf16 (row = col index, 64 v contiguous)
    float* __restrict__ sc1,           // [64][28] fp32
    float* __restrict__ sC)            // [M1*N1*K1]
{
    constexpr int UC = 64 / USPLIT;    // u-chunk length
    constexpr int CN = K1 * N1;
    const int t = threadIdx.x;
    const int ztile = local / USPLIT;
    const int usub  = local - ztile * USPLIT;
    const int z0 = ztile * 64;
    const int u0 = usub * UC;

    const int lane = t & 63;
    const int wave = t >> 6;
    const int ln = lane & 15;
    const int q  = lane >> 4;

    for (int i = t; i < M1 * N1 * K1; i += NTHREADS) sC[i] = Cg[i];
    __syncthreads();

    f32x4 acc[4][K1];
#pragma unroll
    for (int wt = 0; wt < 4; ++wt)
#pragma unroll
        for (int i = 0; i < K1; ++i) acc[wt][i] = (f32x4){0.f, 0.f, 0.f, 0.f};

    for (int uu = 0; uu < UC; ++uu) {
        const int u = u0 + uu;

        // ---- stage A: W[p][w][u][0..63] fp32 -> bf16 sW[w*72+v], float4 coalesced
        {
            const float* wb = Wg + (size_t)u * 64;
#pragma unroll
            for (int it = 0; it < 4; ++it) {
                int i = it * NTHREADS + t;
                int w = i >> 4, v4 = (i & 15) << 2;
                const float4 f = *(const float4*)(wb + (size_t)w * 4096 + v4);
                ushort4 h;
                h.x = f2bf(f.x); h.y = f2bf(f.y); h.z = f2bf(f.z); h.w = f2bf(f.w);
                *(ushort4*)&sW[w * 72 + v4] = h;
            }
        }
        // ---- c1[z][k*N1+n] = sum_m x1[z,u,m] * C[m,n,k]
        for (int i = t; i < 64 * CN; i += NTHREADS) {
            int z = i / CN;
            int r = i - z * CN;          // r = k*N1 + n
            int k = r / N1;
            int n = r - k * N1;
            const float* x1r = x1g + ((size_t)(z0 + z) * 64 + u) * M1;
            float s = 0.f;
#pragma unroll
            for (int m = 0; m < M1; ++m) s += x1r[m] * sC[(m * N1 + n) * K1 + k];
            sc1[z * 28 + r] = s;
        }
        __syncthreads();

        // ---- B tile: sT[(z*K1+k)*72 + v] = bf16( sum_n x2[z,v,n] * c1[z,k,n] )
        // wave-uniform z per iteration -> sc1 reads are LDS broadcasts (b128)
#pragma unroll 1
        for (int i2 = 0; i2 < 16; ++i2) {
            const int z = i2 * 4 + wave;
            const int v = lane;
            float c1r[28];
#pragma unroll
            for (int j = 0; j < (CN + 3) / 4; ++j) {
                float4 f = *(const float4*)&sc1[z * 28 + j * 4];
                c1r[j * 4 + 0] = f.x; c1r[j * 4 + 1] = f.y;
                c1r[j * 4 + 2] = f.z; c1r[j * 4 + 3] = f.w;
            }
            const float* x2r = x2g + ((size_t)(z0 + z) * 64 + v) * N1;
            float xv[N1];
#pragma unroll
            for (int n = 0; n < N1; ++n) xv[n] = x2r[n];
#pragma unroll
            for (int k = 0; k < K1; ++k) {
                float s = 0.f;
#pragma unroll
                for (int n = 0; n < N1; ++n) s += xv[n] * c1r[k * N1 + n];
                sT[(z * K1 + k) * 72 + v] = f2bf(s);
            }
        }
        __syncthreads();

        // ---- MFMA: wave owns all 4 w-tiles x K1 n-tiles
        {
            const unsigned short* pa = &sW[ln * 72];
            const unsigned short* pb = &sT[((wave * K1) * 16 + ln) * 72];
#pragma unroll
            for (int s = 0; s < 2; ++s) {           // K chunks of 32 (v)
                s16x8 af[4];
#pragma unroll
                for (int wt = 0; wt < 4; ++wt)
                    af[wt] = *(const s16x8*)&pa[wt * 16 * 72 + s * 32 + q * 8];
#pragma unroll
                for (int i = 0; i < K1; ++i) {
                    s16x8 bf = *(const s16x8*)&pb[i * 16 * 72 + s * 32 + q * 8];
#pragma unroll
                    for (int wt = 0; wt < 4; ++wt)
                        acc[wt][i] = __builtin_amdgcn_mfma_f32_16x16x32_bf16(
                            af[wt], bf, acc[wt][i], 0, 0, 0);
                }
            }
        }
        __syncthreads();
    }

    // ---- epilogue: D[row=q*4+r in tile][col=ln] ; col = z_local*K1 + k
#pragma unroll
    for (int wt = 0; wt < 4; ++wt) {
#pragma unroll
        for (int i = 0; i < K1; ++i) {
            const int col = (wave * K1 + i) * 16 + ln;
            const int z = col / K1;
            const int k = col - z * K1;
            float* op = outg + (size_t)(z0 + z) * 576 + KOFF + k;
#pragma unroll
            for (int r = 0; r < 4; ++r) {
                int w = wt * 16 + q * 4 + r;
                atomicAdd(op + w * 9, acc[wt][i][r]);
            }
        }
    }
}

__global__ __launch_bounds__(NTHREADS) void tp_kernel(KArgs a)
{
    __shared__ __align__(16) unsigned short sW[64 * 72];    // 9216 B
    __shared__ __align__(16) unsigned short sT[320 * 72];   // 46080 B
    __shared__ __align__(16) float sc1[64 * 28];            // 7168 B
    __shared__ __align__(16) float sC[128];

    const int bid = blockIdx.x;
    const int starts[12] = {0, 16, 48, 112, 144, 160, 224, 256, 320, 352, 368, 432};
    int p = 0;
#pragma unroll
    for (int i = 1; i < 12; ++i) p += (bid >= starts[i]) ? 1 : 0;
    const int local = bid - starts[p];
    const float* Wg = a.W + (size_t)p * 64 * 64 * 64;

    switch (p) {
        case 0:  run_path<1,1,1,0,1>(a.x1[0], a.x2[0], Wg, a.C[0],  a.out, local, sW, sT, sc1, sC); break;
        case 1:  run_path<1,3,3,1,2>(a.x1[0], a.x2[1], Wg, a.C[1],  a.out, local, sW, sT, sc1, sC); break;
        case 2:  run_path<1,5,5,4,4>(a.x1[0], a.x2[2], Wg, a.C[2],  a.out, local, sW, sT, sc1, sC); break;
        case 3:  run_path<3,1,3,1,2>(a.x1[1], a.x2[0], Wg, a.C[3],  a.out, local, sW, sT, sc1, sC); break;
        case 4:  run_path<3,3,1,0,1>(a.x1[1], a.x2[1], Wg, a.C[4],  a.out, local, sW, sT, sc1, sC); break;
        case 5:  run_path<3,3,5,4,4>(a.x1[1], a.x2[1], Wg, a.C[5],  a.out, local, sW, sT, sc1, sC); break;
        case 6:  run_path<3,5,3,1,2>(a.x1[1], a.x2[2], Wg, a.C[6],  a.out, local, sW, sT, sc1, sC); break;
        case 7:  run_path<5,1,5,4,4>(a.x1[2], a.x2[0], Wg, a.C[7],  a.out, local, sW, sT, sc1, sC); break;
        case 8:  run_path<5,3,3,1,2>(a.x1[2], a.x2[1], Wg, a.C[8],  a.out, local, sW, sT, sc1, sC); break;
        case 9:  run_path<5,5,1,0,1>(a.x1[2], a.x2[2], Wg, a.C[9],  a.out, local, sW, sT, sc1, sC); break;
        case 10: run_path<5,5,5,4,4>(a.x1[2], a.x2[2], Wg, a.C[10], a.out, local, sW, sT, sc1, sC); break;
        default: break;
    }
}

extern "C" void kernel_launch(void* const* d_in, const int* in_sizes, int n_in,
                              void* d_out, int out_size, void* d_ws, size_t ws_size,
                              hipStream_t stream)
{
    KArgs a;
    // setup_inputs() dict order: x1_l0, x2_l0, x1_l1, x2_l1, x1_l2, x2_l2, W, C_0..C_10
    a.x1[0] = (const float*)d_in[0];
    a.x2[0] = (const float*)d_in[1];
    a.x1[1] = (const float*)d_in[2];
    a.x2[1] = (const float*)d_in[3];
    a.x1[2] = (const float*)d_in[4];
    a.x2[2] = (const float*)d_in[5];
    a.W     = (const float*)d_in[6];
    for (int p = 0; p < 11; ++p) a.C[p] = (const float*)d_in[7 + p];
    a.out   = (float*)d_out;

    hipMemsetAsync(d_out, 0, (size_t)out_size * sizeof(float), stream);
    tp_kernel<<<dim3(432), NTHREADS, 0, stream>>>(a);
}